// Round 5
// baseline (154.608 us; speedup 1.0000x reference)
//
#include <hip/hip_runtime.h>

// DeepFM fused forward, round 5: MEASUREMENT ROUND.
// Identical kernel to round 4, but launched 3x back-to-back (idempotent:
// each launch fully recomputes and overwrites out). dur_us = overhead + 3K,
// vs round 4's overhead + K  =>  K = (dur_R5 - dur_R4) / 2.

#define RPB 4
#define BATCH 2048
#define NF 151193  // sum(VOCABS)+1

#define OFF0 0
#define OFF1 100000
#define OFF2 150000
#define OFF3 150010
#define OFF4 150013
#define OFF5 150113
#define OFF6 150163
#define OFF7 151163
#define OFF8 151187

typedef float f4 __attribute__((ext_vector_type(4)));

__device__ inline f4 relu4(f4 v) {
    f4 r;
    r.x = fmaxf(v.x, 0.0f); r.y = fmaxf(v.y, 0.0f);
    r.z = fmaxf(v.z, 0.0f); r.w = fmaxf(v.w, 0.0f);
    return r;
}

__global__ __launch_bounds__(512, 4) void deepfm_fused(
    const int* __restrict__ f_user, const int* __restrict__ f_item,
    const int* __restrict__ f_age, const int* __restrict__ f_gender,
    const int* __restrict__ f_city, const int* __restrict__ f_cat,
    const int* __restrict__ f_brand, const int* __restrict__ f_hour,
    const int* __restrict__ f_dev, const float* __restrict__ price,
    const float* __restrict__ e_user, const float* __restrict__ e_item,
    const float* __restrict__ e_age, const float* __restrict__ e_gender,
    const float* __restrict__ e_city, const float* __restrict__ e_cat,
    const float* __restrict__ e_brand, const float* __restrict__ e_hour,
    const float* __restrict__ e_dev,
    const float* __restrict__ w_dense, const float* __restrict__ b_dense,
    const float* __restrict__ fm_v,
    const float* __restrict__ W1, const float* __restrict__ b1,
    const float* __restrict__ W2, const float* __restrict__ b2,
    const float* __restrict__ W3, const float* __restrict__ b3,
    const float* __restrict__ Wo, const float* __restrict__ bo,
    float* __restrict__ out)
{
    __shared__ __align__(16) float x[RPB][96];     // deep_in, zero-padded 77..95
    __shared__ __align__(16) float h1s[RPB][256];
    __shared__ __align__(16) float h2s[RPB][128];
    __shared__ __align__(16) float pred[8192];     // 32 KB partials, reused per layer
    __shared__ float row_extra[RPB];

    const int tid  = threadIdx.x;
    const int base = blockIdx.x * RPB;

    // bias / output-weight prefetch (role-indexed, data-independent)
    const f4 b1v  = ((const f4*)b1)[tid & 63];
    const f4 b2v  = ((const f4*)b2)[tid & 31];
    const f4 b3v  = ((const f4*)b3)[tid & 15];
    const f4 wo_r = ((const f4*)Wo)[tid & 15];
    const float bo_s = bo[0];

    // ---- Phase B: waves 0-1 gather embeddings; wave 2 FM + dense ----
    if (tid < 128) {
        const int r = tid >> 5, l = tid & 31;
        const int gr = base + r;
        if (l < 16) x[r][ 0 + l] = e_user  [f_user[gr]   * 16 + l];
        if (l < 16) x[r][16 + l] = e_item  [f_item[gr]   * 16 + l];
        if (l <  8) x[r][32 + l] = e_age   [f_age[gr]    *  8 + l];
        if (l <  4) x[r][40 + l] = e_gender[f_gender[gr] *  4 + l];
        if (l <  8) x[r][44 + l] = e_city  [f_city[gr]   *  8 + l];
        if (l <  8) x[r][52 + l] = e_cat   [f_cat[gr]    *  8 + l];
        if (l <  8) x[r][60 + l] = e_brand [f_brand[gr]  *  8 + l];
        if (l <  4) x[r][68 + l] = e_hour  [f_hour[gr]   *  4 + l];
        if (l <  4) x[r][72 + l] = e_dev   [f_dev[gr]    *  4 + l];
        if (l == 0) x[r][76]     = price[gr];
        if (l >= 13) x[r][64 + l] = 0.0f;   // zero pad indices 77..95
    } else if (tid < 192) {
        const int r = (tid >> 4) & 3, k = tid & 15;
        const int gr = base + r;
        const int i0 = f_user[gr], i1 = f_item[gr], i2 = f_age[gr];
        const int i3 = f_gender[gr], i4 = f_city[gr], i5 = f_cat[gr];
        const int i6 = f_brand[gr], i7 = f_hour[gr], i8 = f_dev[gr];
        const float px = price[gr] * (1.0f / 1000.0f);
        float v, s, ssq;
        v = fm_v[(NF - 1) * 16 + k];
        s = px * v; ssq = s * s;
        v = fm_v[(OFF0 + i0) * 16 + k]; s += v; ssq += v * v;
        v = fm_v[(OFF1 + i1) * 16 + k]; s += v; ssq += v * v;
        v = fm_v[(OFF2 + i2) * 16 + k]; s += v; ssq += v * v;
        v = fm_v[(OFF3 + i3) * 16 + k]; s += v; ssq += v * v;
        v = fm_v[(OFF4 + i4) * 16 + k]; s += v; ssq += v * v;
        v = fm_v[(OFF5 + i5) * 16 + k]; s += v; ssq += v * v;
        v = fm_v[(OFF6 + i6) * 16 + k]; s += v; ssq += v * v;
        v = fm_v[(OFF7 + i7) * 16 + k]; s += v; ssq += v * v;
        v = fm_v[(OFF8 + i8) * 16 + k]; s += v; ssq += v * v;
        float q = 0.5f * (s * s - ssq);
        if (k == 0) {
            float d = b_dense[0] + px * w_dense[NF - 1];
            d += w_dense[OFF0 + i0];
            d += w_dense[OFF1 + i1];
            d += w_dense[OFF2 + i2];
            d += w_dense[OFF3 + i3];
            d += w_dense[OFF4 + i4];
            d += w_dense[OFF5 + i5];
            d += w_dense[OFF6 + i6];
            d += w_dense[OFF7 + i7];
            d += w_dense[OFF8 + i8];
            q += d;
        }
        q += __shfl_xor(q, 8);
        q += __shfl_xor(q, 4);
        q += __shfl_xor(q, 2);
        q += __shfl_xor(q, 1);
        if (k == 0) row_extra[r] = q;
    }
    __syncthreads();   // (1) x, row_extra ready

    const f4* hv1 = (const f4*)h1s;   // row r = 64 f4
    const f4* hv2 = (const f4*)h2s;   // row r = 32 f4
    f4* pv = (f4*)pred;

    // ---- Layer 1: (4 x 96) @ (96 x 256), K split 8 ways (12 k each) ----
    {
        const int kg = tid >> 6, ct = tid & 63;       // kg uniform per wave
        const f4* W1v = (const f4*)W1;                // row i = 64 f4
        const f4* xv  = (const f4*)x;                 // row r = 24 f4
        f4 acc0 = 0, acc1 = 0, acc2 = 0, acc3 = 0;
        #pragma unroll
        for (int c = 0; c < 3; ++c) {
            const int i = 12 * kg + 4 * c, q = 3 * kg + c;
            f4 xa0 = xv[ 0 + q];
            f4 xa1 = xv[24 + q];
            f4 xa2 = xv[48 + q];
            f4 xa3 = xv[72 + q];
            f4 w0 = (i + 0 < 77) ? W1v[(i + 0) * 64 + ct] : (f4)0.0f;
            f4 w1 = (i + 1 < 77) ? W1v[(i + 1) * 64 + ct] : (f4)0.0f;
            f4 w2 = (i + 2 < 77) ? W1v[(i + 2) * 64 + ct] : (f4)0.0f;
            f4 w3 = (i + 3 < 77) ? W1v[(i + 3) * 64 + ct] : (f4)0.0f;
            acc0 += xa0.x * w0 + xa0.y * w1 + xa0.z * w2 + xa0.w * w3;
            acc1 += xa1.x * w0 + xa1.y * w1 + xa1.z * w2 + xa1.w * w3;
            acc2 += xa2.x * w0 + xa2.y * w1 + xa2.z * w2 + xa2.w * w3;
            acc3 += xa3.x * w0 + xa3.y * w1 + xa3.z * w2 + xa3.w * w3;
        }
        pv[(kg * 4 + 0) * 64 + ct] = acc0;
        pv[(kg * 4 + 1) * 64 + ct] = acc1;
        pv[(kg * 4 + 2) * 64 + ct] = acc2;
        pv[(kg * 4 + 3) * 64 + ct] = acc3;
    }
    __syncthreads();   // (2) L1 partials ready
    if (tid < 256) {   // reduce 8 partials + bias + relu -> h1s
        const int r = tid >> 6, c4 = tid & 63;
        f4 s = 0;
        #pragma unroll
        for (int kg = 0; kg < 8; ++kg) s += pv[(kg * 4 + r) * 64 + c4];
        s += b1v;
        ((f4*)h1s)[r * 64 + c4] = relu4(s);
    }
    __syncthreads();   // (3) h1 ready

    // ---- Layer 2: (4 x 256) @ (256 x 128), K split 16 ways (16 k each) ----
    {
        const int kg = tid >> 5, ct = tid & 31;
        const f4* W2v = (const f4*)W2;                // row k = 32 f4
        f4 acc0 = 0, acc1 = 0, acc2 = 0, acc3 = 0;
        #pragma unroll
        for (int c = 0; c < 4; ++c) {
            const int q = 4 * kg + c;                 // f4-chunk of K
            f4 xa0 = hv1[  0 + q];
            f4 xa1 = hv1[ 64 + q];
            f4 xa2 = hv1[128 + q];
            f4 xa3 = hv1[192 + q];
            f4 w0 = W2v[(4 * q + 0) * 32 + ct];
            f4 w1 = W2v[(4 * q + 1) * 32 + ct];
            f4 w2 = W2v[(4 * q + 2) * 32 + ct];
            f4 w3 = W2v[(4 * q + 3) * 32 + ct];
            acc0 += xa0.x * w0 + xa0.y * w1 + xa0.z * w2 + xa0.w * w3;
            acc1 += xa1.x * w0 + xa1.y * w1 + xa1.z * w2 + xa1.w * w3;
            acc2 += xa2.x * w0 + xa2.y * w1 + xa2.z * w2 + xa2.w * w3;
            acc3 += xa3.x * w0 + xa3.y * w1 + xa3.z * w2 + xa3.w * w3;
        }
        pv[(kg * 4 + 0) * 32 + ct] = acc0;
        pv[(kg * 4 + 1) * 32 + ct] = acc1;
        pv[(kg * 4 + 2) * 32 + ct] = acc2;
        pv[(kg * 4 + 3) * 32 + ct] = acc3;
    }
    __syncthreads();   // (4) L2 partials ready
    if (tid < 128) {   // reduce 16 partials + bias + relu -> h2s
        const int r = tid >> 5, c4 = tid & 31;
        f4 s = 0;
        #pragma unroll
        for (int kg = 0; kg < 16; ++kg) s += pv[(kg * 4 + r) * 32 + c4];
        s += b2v;
        ((f4*)h2s)[r * 32 + c4] = relu4(s);
    }
    __syncthreads();   // (5) h2 ready

    // ---- Layer 3: (4 x 128) @ (128 x 64), K split 32 ways (4 k each) ----
    {
        const int kg = tid >> 4, ct = tid & 15;
        const f4* W3v = (const f4*)W3;                // row k = 16 f4
        f4 acc0 = 0, acc1 = 0, acc2 = 0, acc3 = 0;
        {
            const int q = kg;
            f4 xa0 = hv2[ 0 + q];
            f4 xa1 = hv2[32 + q];
            f4 xa2 = hv2[64 + q];
            f4 xa3 = hv2[96 + q];
            f4 w0 = W3v[(4 * q + 0) * 16 + ct];
            f4 w1 = W3v[(4 * q + 1) * 16 + ct];
            f4 w2 = W3v[(4 * q + 2) * 16 + ct];
            f4 w3 = W3v[(4 * q + 3) * 16 + ct];
            acc0 = xa0.x * w0 + xa0.y * w1 + xa0.z * w2 + xa0.w * w3;
            acc1 = xa1.x * w0 + xa1.y * w1 + xa1.z * w2 + xa1.w * w3;
            acc2 = xa2.x * w0 + xa2.y * w1 + xa2.z * w2 + xa2.w * w3;
            acc3 = xa3.x * w0 + xa3.y * w1 + xa3.z * w2 + xa3.w * w3;
        }
        pv[(kg * 4 + 0) * 16 + ct] = acc0;
        pv[(kg * 4 + 1) * 16 + ct] = acc1;
        pv[(kg * 4 + 2) * 16 + ct] = acc2;
        pv[(kg * 4 + 3) * 16 + ct] = acc3;
    }
    __syncthreads();   // (6) L3 partials ready

    // ---- reduce3 + relu + output dot, fused (one wave) ----
    if (tid < 64) {
        const int r = tid >> 4, c4 = tid & 15;
        f4 s = 0;
        #pragma unroll
        for (int kg = 0; kg < 32; ++kg) s += pv[(kg * 4 + r) * 16 + c4];
        s += b3v;
        f4 h = relu4(s);
        float t = h.x * wo_r.x + h.y * wo_r.y + h.z * wo_r.z + h.w * wo_r.w;
        t += __shfl_xor(t, 8);
        t += __shfl_xor(t, 4);
        t += __shfl_xor(t, 2);
        t += __shfl_xor(t, 1);
        if (c4 == 0) out[base + r] = t + bo_s + row_extra[r];
    }
}

extern "C" void kernel_launch(void* const* d_in, const int* in_sizes, int n_in,
                              void* d_out, int out_size, void* d_ws, size_t ws_size,
                              hipStream_t stream) {
    const int*   f_user   = (const int*)  d_in[0];
    const int*   f_item   = (const int*)  d_in[1];
    const int*   f_age    = (const int*)  d_in[2];
    const int*   f_gender = (const int*)  d_in[3];
    const int*   f_city   = (const int*)  d_in[4];
    const int*   f_cat    = (const int*)  d_in[5];
    const int*   f_brand  = (const int*)  d_in[6];
    const int*   f_hour   = (const int*)  d_in[7];
    const int*   f_dev    = (const int*)  d_in[8];
    const float* price    = (const float*)d_in[9];
    const float* e_user   = (const float*)d_in[10];
    const float* e_item   = (const float*)d_in[11];
    const float* e_age    = (const float*)d_in[12];
    const float* e_gender = (const float*)d_in[13];
    const float* e_city   = (const float*)d_in[14];
    const float* e_cat    = (const float*)d_in[15];
    const float* e_brand  = (const float*)d_in[16];
    const float* e_hour   = (const float*)d_in[17];
    const float* e_dev    = (const float*)d_in[18];
    const float* w_dense  = (const float*)d_in[19];
    const float* b_dense  = (const float*)d_in[20];
    const float* fm_v     = (const float*)d_in[21];
    const float* W1       = (const float*)d_in[22];
    const float* b1       = (const float*)d_in[23];
    const float* W2       = (const float*)d_in[24];
    const float* b2       = (const float*)d_in[25];
    const float* W3       = (const float*)d_in[26];
    const float* b3       = (const float*)d_in[27];
    const float* Wo       = (const float*)d_in[28];
    const float* bo       = (const float*)d_in[29];
    float* out = (float*)d_out;

    dim3 grid(BATCH / RPB);   // 512 blocks of 8 waves
    dim3 block(512);
    // MEASUREMENT: 3 identical idempotent launches. dur = overhead + 3K.
    for (int rep = 0; rep < 3; ++rep) {
        deepfm_fused<<<grid, block, 0, stream>>>(
            f_user, f_item, f_age, f_gender, f_city, f_cat, f_brand, f_hour, f_dev,
            price, e_user, e_item, e_age, e_gender, e_city, e_cat, e_brand, e_hour,
            e_dev, w_dense, b_dense, fm_v, W1, b1, W2, b2, W3, b3, Wo, bo, out);
    }
}

// Round 6
// 129.400 us; speedup vs baseline: 1.1948x; 1.1948x over previous
//
#include <hip/hip_runtime.h>

// DeepFM fused forward, round 6: halve per-CU L2 weight traffic.
// RPB=8, grid=256 blocks x 512 threads -> exactly 1 block/CU, 8 waves/CU.
// Each CU reads the 240 KB weight set once (was twice at RPB=4/512 blocks).
// K split 8/16/32 ways; 8-row f4 accumulators; 64 KB LDS partial buffer.

#define RPB 8
#define BATCH 2048
#define NF 151193  // sum(VOCABS)+1

#define OFF0 0
#define OFF1 100000
#define OFF2 150000
#define OFF3 150010
#define OFF4 150013
#define OFF5 150113
#define OFF6 150163
#define OFF7 151163
#define OFF8 151187

typedef float f4 __attribute__((ext_vector_type(4)));

__device__ inline f4 relu4(f4 v) {
    f4 r;
    r.x = fmaxf(v.x, 0.0f); r.y = fmaxf(v.y, 0.0f);
    r.z = fmaxf(v.z, 0.0f); r.w = fmaxf(v.w, 0.0f);
    return r;
}

__global__ __launch_bounds__(512, 2) void deepfm_fused(
    const int* __restrict__ f_user, const int* __restrict__ f_item,
    const int* __restrict__ f_age, const int* __restrict__ f_gender,
    const int* __restrict__ f_city, const int* __restrict__ f_cat,
    const int* __restrict__ f_brand, const int* __restrict__ f_hour,
    const int* __restrict__ f_dev, const float* __restrict__ price,
    const float* __restrict__ e_user, const float* __restrict__ e_item,
    const float* __restrict__ e_age, const float* __restrict__ e_gender,
    const float* __restrict__ e_city, const float* __restrict__ e_cat,
    const float* __restrict__ e_brand, const float* __restrict__ e_hour,
    const float* __restrict__ e_dev,
    const float* __restrict__ w_dense, const float* __restrict__ b_dense,
    const float* __restrict__ fm_v,
    const float* __restrict__ W1, const float* __restrict__ b1,
    const float* __restrict__ W2, const float* __restrict__ b2,
    const float* __restrict__ W3, const float* __restrict__ b3,
    const float* __restrict__ Wo, const float* __restrict__ bo,
    float* __restrict__ out)
{
    __shared__ __align__(16) float x[RPB][96];     // deep_in, zero-padded 77..95
    __shared__ __align__(16) float h1s[RPB][256];
    __shared__ __align__(16) float h2s[RPB][128];
    __shared__ __align__(16) float pred[16384];    // 64 KB partials, reused per layer
    __shared__ float row_extra[RPB];

    const int tid  = threadIdx.x;
    const int base = blockIdx.x * RPB;

    // bias / output-weight prefetch (role-indexed, data-independent)
    const f4 b1v  = ((const f4*)b1)[tid & 63];
    const f4 b2v  = ((const f4*)b2)[tid & 31];
    const f4 b3v  = ((const f4*)b3)[tid & 15];
    const f4 wo_r = ((const f4*)Wo)[tid & 15];
    const float bo_s = bo[0];

    // ---- Gather: waves 0-3 embeddings (8 rows x 32 lanes); waves 4-5 FM+dense ----
    if (tid < 256) {
        const int r = tid >> 5, l = tid & 31;
        const int gr = base + r;
        if (l < 16) x[r][ 0 + l] = e_user  [f_user[gr]   * 16 + l];
        if (l < 16) x[r][16 + l] = e_item  [f_item[gr]   * 16 + l];
        if (l <  8) x[r][32 + l] = e_age   [f_age[gr]    *  8 + l];
        if (l <  4) x[r][40 + l] = e_gender[f_gender[gr] *  4 + l];
        if (l <  8) x[r][44 + l] = e_city  [f_city[gr]   *  8 + l];
        if (l <  8) x[r][52 + l] = e_cat   [f_cat[gr]    *  8 + l];
        if (l <  8) x[r][60 + l] = e_brand [f_brand[gr]  *  8 + l];
        if (l <  4) x[r][68 + l] = e_hour  [f_hour[gr]   *  4 + l];
        if (l <  4) x[r][72 + l] = e_dev   [f_dev[gr]    *  4 + l];
        if (l == 0) x[r][76]     = price[gr];
        if (l >= 13) x[r][64 + l] = 0.0f;   // zero pad indices 77..95
    } else if (tid < 384) {
        const int r = (tid >> 4) & 7, k = tid & 15;
        const int gr = base + r;
        const int i0 = f_user[gr], i1 = f_item[gr], i2 = f_age[gr];
        const int i3 = f_gender[gr], i4 = f_city[gr], i5 = f_cat[gr];
        const int i6 = f_brand[gr], i7 = f_hour[gr], i8 = f_dev[gr];
        const float px = price[gr] * (1.0f / 1000.0f);
        float v, s, ssq;
        v = fm_v[(NF - 1) * 16 + k];
        s = px * v; ssq = s * s;
        v = fm_v[(OFF0 + i0) * 16 + k]; s += v; ssq += v * v;
        v = fm_v[(OFF1 + i1) * 16 + k]; s += v; ssq += v * v;
        v = fm_v[(OFF2 + i2) * 16 + k]; s += v; ssq += v * v;
        v = fm_v[(OFF3 + i3) * 16 + k]; s += v; ssq += v * v;
        v = fm_v[(OFF4 + i4) * 16 + k]; s += v; ssq += v * v;
        v = fm_v[(OFF5 + i5) * 16 + k]; s += v; ssq += v * v;
        v = fm_v[(OFF6 + i6) * 16 + k]; s += v; ssq += v * v;
        v = fm_v[(OFF7 + i7) * 16 + k]; s += v; ssq += v * v;
        v = fm_v[(OFF8 + i8) * 16 + k]; s += v; ssq += v * v;
        float q = 0.5f * (s * s - ssq);
        if (k == 0) {
            float d = b_dense[0] + px * w_dense[NF - 1];
            d += w_dense[OFF0 + i0];
            d += w_dense[OFF1 + i1];
            d += w_dense[OFF2 + i2];
            d += w_dense[OFF3 + i3];
            d += w_dense[OFF4 + i4];
            d += w_dense[OFF5 + i5];
            d += w_dense[OFF6 + i6];
            d += w_dense[OFF7 + i7];
            d += w_dense[OFF8 + i8];
            q += d;
        }
        q += __shfl_xor(q, 8);
        q += __shfl_xor(q, 4);
        q += __shfl_xor(q, 2);
        q += __shfl_xor(q, 1);
        if (k == 0) row_extra[r] = q;
    }
    __syncthreads();   // (1) x, row_extra ready

    const f4* hv1 = (const f4*)h1s;   // row r = 64 f4
    const f4* hv2 = (const f4*)h2s;   // row r = 32 f4
    f4* pv = (f4*)pred;

    // ---- Layer 1: (8 x 96) @ (96 x 256), K split 8 ways (12 k each) ----
    {
        const int kg = tid >> 6, ct = tid & 63;       // kg uniform per wave
        const f4* W1v = (const f4*)W1;                // row i = 64 f4
        const f4* xv  = (const f4*)x;                 // row r = 24 f4
        f4 acc[RPB];
        #pragma unroll
        for (int r = 0; r < RPB; ++r) acc[r] = 0;
        #pragma unroll
        for (int c = 0; c < 3; ++c) {
            const int i = 12 * kg + 4 * c, q = 3 * kg + c;
            f4 w0 = (i + 0 < 77) ? W1v[(i + 0) * 64 + ct] : (f4)0.0f;
            f4 w1 = (i + 1 < 77) ? W1v[(i + 1) * 64 + ct] : (f4)0.0f;
            f4 w2 = (i + 2 < 77) ? W1v[(i + 2) * 64 + ct] : (f4)0.0f;
            f4 w3 = (i + 3 < 77) ? W1v[(i + 3) * 64 + ct] : (f4)0.0f;
            #pragma unroll
            for (int r = 0; r < RPB; ++r) {
                f4 xa = xv[r * 24 + q];
                acc[r] += xa.x * w0 + xa.y * w1 + xa.z * w2 + xa.w * w3;
            }
        }
        #pragma unroll
        for (int r = 0; r < RPB; ++r) pv[(kg * 8 + r) * 64 + ct] = acc[r];
    }
    __syncthreads();   // (2) L1 partials ready
    {   // reduce 8 partials + bias + relu -> h1s : 512 outputs f4, 512 threads
        const int r = tid >> 6, c4 = tid & 63;
        f4 s = 0;
        #pragma unroll
        for (int kg = 0; kg < 8; ++kg) s += pv[(kg * 8 + r) * 64 + c4];
        s += b1v;
        ((f4*)h1s)[r * 64 + c4] = relu4(s);
    }
    __syncthreads();   // (3) h1 ready

    // ---- Layer 2: (8 x 256) @ (256 x 128), K split 16 ways (16 k each) ----
    {
        const int kg = tid >> 5, ct = tid & 31;
        const f4* W2v = (const f4*)W2;                // row k = 32 f4
        f4 acc[RPB];
        #pragma unroll
        for (int r = 0; r < RPB; ++r) acc[r] = 0;
        #pragma unroll
        for (int c = 0; c < 4; ++c) {
            const int q = 4 * kg + c;                 // f4-chunk of K
            f4 w0 = W2v[(4 * q + 0) * 32 + ct];
            f4 w1 = W2v[(4 * q + 1) * 32 + ct];
            f4 w2 = W2v[(4 * q + 2) * 32 + ct];
            f4 w3 = W2v[(4 * q + 3) * 32 + ct];
            #pragma unroll
            for (int r = 0; r < RPB; ++r) {
                f4 xa = hv1[r * 64 + q];
                acc[r] += xa.x * w0 + xa.y * w1 + xa.z * w2 + xa.w * w3;
            }
        }
        #pragma unroll
        for (int r = 0; r < RPB; ++r) pv[(kg * 8 + r) * 32 + ct] = acc[r];
    }
    __syncthreads();   // (4) L2 partials ready
    if (tid < 256) {   // reduce 16 partials + bias + relu -> h2s : 256 outputs f4
        const int r = tid >> 5, c4 = tid & 31;
        f4 s = 0;
        #pragma unroll
        for (int kg = 0; kg < 16; ++kg) s += pv[(kg * 8 + r) * 32 + c4];
        s += b2v;
        ((f4*)h2s)[r * 32 + c4] = relu4(s);
    }
    __syncthreads();   // (5) h2 ready

    // ---- Layer 3: (8 x 128) @ (128 x 64), K split 32 ways (4 k each) ----
    {
        const int kg = tid >> 4, ct = tid & 15;
        const f4* W3v = (const f4*)W3;                // row k = 16 f4
        const int q = kg;
        f4 w0 = W3v[(4 * q + 0) * 16 + ct];
        f4 w1 = W3v[(4 * q + 1) * 16 + ct];
        f4 w2 = W3v[(4 * q + 2) * 16 + ct];
        f4 w3 = W3v[(4 * q + 3) * 16 + ct];
        f4 acc[RPB];
        #pragma unroll
        for (int r = 0; r < RPB; ++r) {
            f4 xa = hv2[r * 32 + q];
            acc[r] = xa.x * w0 + xa.y * w1 + xa.z * w2 + xa.w * w3;
        }
        #pragma unroll
        for (int r = 0; r < RPB; ++r) pv[(kg * 8 + r) * 16 + ct] = acc[r];
    }
    __syncthreads();   // (6) L3 partials ready

    // ---- reduce3 + relu + output dot, fused (waves 0-1) ----
    if (tid < 128) {
        const int r = tid >> 4, c4 = tid & 15;
        f4 s = 0;
        #pragma unroll
        for (int kg = 0; kg < 32; ++kg) s += pv[(kg * 8 + r) * 16 + c4];
        s += b3v;
        f4 h = relu4(s);
        float t = h.x * wo_r.x + h.y * wo_r.y + h.z * wo_r.z + h.w * wo_r.w;
        t += __shfl_xor(t, 8);
        t += __shfl_xor(t, 4);
        t += __shfl_xor(t, 2);
        t += __shfl_xor(t, 1);
        if (c4 == 0) out[base + r] = t + bo_s + row_extra[r];
    }
}

extern "C" void kernel_launch(void* const* d_in, const int* in_sizes, int n_in,
                              void* d_out, int out_size, void* d_ws, size_t ws_size,
                              hipStream_t stream) {
    const int*   f_user   = (const int*)  d_in[0];
    const int*   f_item   = (const int*)  d_in[1];
    const int*   f_age    = (const int*)  d_in[2];
    const int*   f_gender = (const int*)  d_in[3];
    const int*   f_city   = (const int*)  d_in[4];
    const int*   f_cat    = (const int*)  d_in[5];
    const int*   f_brand  = (const int*)  d_in[6];
    const int*   f_hour   = (const int*)  d_in[7];
    const int*   f_dev    = (const int*)  d_in[8];
    const float* price    = (const float*)d_in[9];
    const float* e_user   = (const float*)d_in[10];
    const float* e_item   = (const float*)d_in[11];
    const float* e_age    = (const float*)d_in[12];
    const float* e_gender = (const float*)d_in[13];
    const float* e_city   = (const float*)d_in[14];
    const float* e_cat    = (const float*)d_in[15];
    const float* e_brand  = (const float*)d_in[16];
    const float* e_hour   = (const float*)d_in[17];
    const float* e_dev    = (const float*)d_in[18];
    const float* w_dense  = (const float*)d_in[19];
    const float* b_dense  = (const float*)d_in[20];
    const float* fm_v     = (const float*)d_in[21];
    const float* W1       = (const float*)d_in[22];
    const float* b1       = (const float*)d_in[23];
    const float* W2       = (const float*)d_in[24];
    const float* b2       = (const float*)d_in[25];
    const float* W3       = (const float*)d_in[26];
    const float* b3       = (const float*)d_in[27];
    const float* Wo       = (const float*)d_in[28];
    const float* bo       = (const float*)d_in[29];
    float* out = (float*)d_out;

    dim3 grid(BATCH / RPB);   // 256 blocks -> 1 block/CU, 8 waves/CU
    dim3 block(512);
    deepfm_fused<<<grid, block, 0, stream>>>(
        f_user, f_item, f_age, f_gender, f_city, f_cat, f_brand, f_hour, f_dev,
        price, e_user, e_item, e_age, e_gender, e_city, e_cat, e_brand, e_hour,
        e_dev, w_dense, b_dense, fm_v, W1, b1, W2, b2, W3, b3, Wo, bo, out);
}